// Round 6
// baseline (205.428 us; speedup 1.0000x reference)
//
#include <hip/hip_runtime.h>

#define NB 8
#define NN 2048
#define NM 8192
#define NC 64
#define ND 64
#define NK 16

#define PARTS 8     // lanes per query
#define PPT 256     // points per lane
#define QPB 64      // queries per block
#define THREADS 512
#define NG 8        // groups of 32 points per lane
#define G4 33       // float4 units per group (32 + 1 pad -> +1 quad shift)
#define CH4 265     // float4 units per part (8*33 + 1 -> +1 quad shift)
#define CAP 40      // candidate slots per query
#define TMARGIN 2.0e-3f  // >= 60x worst-case numeric error of the t-filter

// ---------------------------------------------------------------------------
// Kernel 1: feats = transpose(features), x = feats @ W1^T + b1  (unchanged)
// ---------------------------------------------------------------------------
__global__ __launch_bounds__(256) void feats_linear_kernel(
    const float* __restrict__ features, const float* __restrict__ W1,
    const float* __restrict__ b1, float* __restrict__ out_feats,
    float* __restrict__ out_x) {
  __shared__ float tile[NC][68];
  __shared__ float Wt[NC][68];

  const int b = blockIdx.y;
  const int n0 = blockIdx.x * 64;
  const int t = threadIdx.x;
  const int lane = t & 63;
  const int grp = t >> 6;

  for (int c = grp; c < NC; c += 4)
    tile[c][lane] = features[((size_t)(b * NC + c) * NN) + n0 + lane];
  for (int i = t; i < NC * ND; i += 256) {
    const int d = i >> 6, c = i & 63;
    Wt[c][d] = W1[i];
  }
  __syncthreads();

  for (int j = grp; j < 64; j += 4)
    out_feats[((size_t)(b * NN + n0 + j) * NC) + lane] = tile[lane][j];

  const int d = lane;
  float acc[16];
  const float bd = b1[d];
#pragma unroll
  for (int jj = 0; jj < 16; jj++) acc[jj] = bd;

  const float4* tv = (const float4*)&tile[0][0];
  for (int c = 0; c < NC; c++) {
    const float w = Wt[c][d];
#pragma unroll
    for (int q = 0; q < 4; q++) {
      const float4 v = tv[c * 17 + grp * 4 + q];
      acc[q * 4 + 0] = fmaf(v.x, w, acc[q * 4 + 0]);
      acc[q * 4 + 1] = fmaf(v.y, w, acc[q * 4 + 1]);
      acc[q * 4 + 2] = fmaf(v.z, w, acc[q * 4 + 2]);
      acc[q * 4 + 3] = fmaf(v.w, w, acc[q * 4 + 3]);
    }
  }
#pragma unroll
  for (int jj = 0; jj < 16; jj++) {
    const int j = grp * 16 + jj;
    out_x[((size_t)(b * NN + n0 + j) * ND) + d] = acc[jj];
  }
}

// ---------------------------------------------------------------------------
// Kernel 2: exact stable kNN. AoS (x,y,z,|p|^2) LDS, t-space filter,
// barrier-gated serial exact phase 3 (R3-proven structure).
// ---------------------------------------------------------------------------
__device__ __forceinline__ float d2rn(float qx, float qy, float qz, float x,
                                      float y, float z) {
  const float dx = __fsub_rn(qx, x);
  const float dy = __fsub_rn(qy, y);
  const float dz = __fsub_rn(qz, z);
  return __fadd_rn(__fadd_rn(__fmul_rn(dx, dx), __fmul_rn(dy, dy)),
                   __fmul_rn(dz, dz));
}

__device__ __forceinline__ int slot4(int i) {
  return (i >> 8) * CH4 + ((i & 255) >> 5) * G4 + (i & 31);
}

#define CE(a, i, j)                     \
  {                                     \
    const float lo = fminf(a[i], a[j]); \
    const float hi = fmaxf(a[i], a[j]); \
    a[i] = lo;                          \
    a[j] = hi;                          \
  }

#define SORT8(d)                                  \
  CE(d, 0, 1) CE(d, 2, 3) CE(d, 4, 5) CE(d, 6, 7) \
  CE(d, 0, 2) CE(d, 1, 3) CE(d, 4, 6) CE(d, 5, 7) \
  CE(d, 1, 2) CE(d, 5, 6)                         \
  CE(d, 0, 4) CE(d, 1, 5) CE(d, 2, 6) CE(d, 3, 7) \
  CE(d, 2, 4) CE(d, 3, 5)                         \
  CE(d, 1, 2) CE(d, 3, 4) CE(d, 5, 6)

#define BITONIC16(L)                                                      \
  CE(L, 0, 8) CE(L, 1, 9) CE(L, 2, 10) CE(L, 3, 11) CE(L, 4, 12)          \
  CE(L, 5, 13) CE(L, 6, 14) CE(L, 7, 15)                                  \
  CE(L, 0, 4) CE(L, 1, 5) CE(L, 2, 6) CE(L, 3, 7) CE(L, 8, 12)            \
  CE(L, 9, 13) CE(L, 10, 14) CE(L, 11, 15)                                \
  CE(L, 0, 2) CE(L, 1, 3) CE(L, 4, 6) CE(L, 5, 7) CE(L, 8, 10)            \
  CE(L, 9, 11) CE(L, 12, 14) CE(L, 13, 15)                                \
  CE(L, 0, 1) CE(L, 2, 3) CE(L, 4, 5) CE(L, 6, 7) CE(L, 8, 9)             \
  CE(L, 10, 11) CE(L, 12, 13) CE(L, 14, 15)

__global__ __launch_bounds__(THREADS, 8) void knn_kernel(
    const float* __restrict__ xyz, const float* __restrict__ xyz_fp,
    float* __restrict__ out_knn) {
  __shared__ float4 pts4[PARTS * CH4];          // 33920 B
  __shared__ unsigned short cand[QPB * CAP];    // 5120 B
  __shared__ int ccnt[QPB];                     // 256 B

  const int b = blockIdx.y;
  const int t = threadIdx.x;
  const int ql = t >> 3;   // 0..63
  const int part = t & 7;  // 0..7

  if (t < QPB) ccnt[t] = 0;

  // ---- stage points as (x, y, z, |p|^2) ----
  const float* P = xyz + (size_t)b * NN * 3;
  for (int i = t; i < NN; i += THREADS) {
    const float x = P[3 * i + 0], y = P[3 * i + 1], z = P[3 * i + 2];
    pts4[slot4(i)] = make_float4(x, y, z, fmaf(x, x, fmaf(y, y, z * z)));
  }
  __syncthreads();

  const int q = blockIdx.x * QPB + ql;
  const float* Q = xyz_fp + ((size_t)b * NM + q) * 3;
  const float qx = Q[0], qy = Q[1], qz = Q[2];
  const float n2x = -2.0f * qx, n2y = -2.0f * qy, n2z = -2.0f * qz;

  const int pbase = part * CH4;

  // ---- pass 1: per-group min of t = d2 - |q|^2 (monotone in d2) ----
  float gmin[NG];
#pragma unroll
  for (int g = 0; g < NG; g++) {
    const int gb = pbase + g * G4;
    float gm = 3.0e38f;
#pragma unroll
    for (int s = 0; s < 8; s++) {
      const float4 p0 = pts4[gb + s * 4 + 0];
      const float4 p1 = pts4[gb + s * 4 + 1];
      const float4 p2 = pts4[gb + s * 4 + 2];
      const float4 p3 = pts4[gb + s * 4 + 3];
      const float t0 = fmaf(p0.x, n2x, fmaf(p0.y, n2y, fmaf(p0.z, n2z, p0.w)));
      const float t1 = fmaf(p1.x, n2x, fmaf(p1.y, n2y, fmaf(p1.z, n2z, p1.w)));
      const float t2 = fmaf(p2.x, n2x, fmaf(p2.y, n2y, fmaf(p2.z, n2z, p2.w)));
      const float t3 = fmaf(p3.x, n2x, fmaf(p3.y, n2y, fmaf(p3.z, n2z, p3.w)));
      gm = fminf(gm, fminf(fminf(t0, t1), fminf(t2, t3)));
    }
    gmin[g] = gm;
  }

  // ---- T = 16th-smallest of the 64 group-mins (each from a distinct point,
  //      so at least 16 points satisfy t <= T); margin covers t-vs-d2 rounding ----
  float s[16];
  {
    float g8[NG];
#pragma unroll
    for (int g = 0; g < NG; g++) g8[g] = gmin[g];
    SORT8(g8)
#pragma unroll
    for (int j = 0; j < 8; j++) s[j] = g8[j];
#pragma unroll
    for (int j = 8; j < 16; j++) s[j] = 3.0e38f;
  }
#pragma unroll
  for (int mask = 1; mask <= 4; mask <<= 1) {
    float B[16];
#pragma unroll
    for (int j = 0; j < 16; j++) B[j] = __shfl_xor(s[j], mask, 64);
    float L[16];
#pragma unroll
    for (int j = 0; j < 16; j++) L[j] = fminf(s[j], B[15 - j]);
    BITONIC16(L)
#pragma unroll
    for (int j = 0; j < 16; j++) s[j] = L[j];
  }
  const float Tf = s[15] + TMARGIN;

  // ---- pass 2: scan groups with gmin <= Tf, append candidates ----
  int gm_mask = 0;
#pragma unroll
  for (int g = 0; g < NG; g++) gm_mask |= (gmin[g] <= Tf) ? (1 << g) : 0;

  while (gm_mask) {
    const int g = __ffs(gm_mask) - 1;
    gm_mask &= gm_mask - 1;
    const int gb = pbase + g * G4;
    const int ibase = part * PPT + g * 32;
#pragma unroll
    for (int s2 = 0; s2 < 8; s2++) {
      const float4 p0 = pts4[gb + s2 * 4 + 0];
      const float4 p1 = pts4[gb + s2 * 4 + 1];
      const float4 p2 = pts4[gb + s2 * 4 + 2];
      const float4 p3 = pts4[gb + s2 * 4 + 3];
      const float t0 = fmaf(p0.x, n2x, fmaf(p0.y, n2y, fmaf(p0.z, n2z, p0.w)));
      const float t1 = fmaf(p1.x, n2x, fmaf(p1.y, n2y, fmaf(p1.z, n2z, p1.w)));
      const float t2 = fmaf(p2.x, n2x, fmaf(p2.y, n2y, fmaf(p2.z, n2z, p2.w)));
      const float t3 = fmaf(p3.x, n2x, fmaf(p3.y, n2y, fmaf(p3.z, n2z, p3.w)));
      if (fminf(fminf(t0, t1), fminf(t2, t3)) <= Tf) {
        if (t0 <= Tf) {
          const int pos = atomicAdd(&ccnt[ql], 1);
          if (pos < CAP) cand[ql * CAP + pos] = (unsigned short)(ibase + s2 * 4 + 0);
        }
        if (t1 <= Tf) {
          const int pos = atomicAdd(&ccnt[ql], 1);
          if (pos < CAP) cand[ql * CAP + pos] = (unsigned short)(ibase + s2 * 4 + 1);
        }
        if (t2 <= Tf) {
          const int pos = atomicAdd(&ccnt[ql], 1);
          if (pos < CAP) cand[ql * CAP + pos] = (unsigned short)(ibase + s2 * 4 + 2);
        }
        if (t3 <= Tf) {
          const int pos = atomicAdd(&ccnt[ql], 1);
          if (pos < CAP) cand[ql * CAP + pos] = (unsigned short)(ibase + s2 * 4 + 3);
        }
      }
    }
  }
  __syncthreads();  // publish cand/ccnt to all lanes

  // ---- phase 3: exact stable top-16 by (d2, idx) u64 chain (R3-proven) ----
  if (part == 0) {
    const int cnt = ccnt[ql];
    unsigned long long kb[NK];
#pragma unroll
    for (int j = 0; j < NK; j++) kb[j] = ~0ULL;

    if (cnt >= NK && cnt <= CAP) {
      for (int c = 0; c < cnt; c++) {
        const int i = cand[ql * CAP + c];
        const float4 p = pts4[slot4(i)];
        const float u = d2rn(qx, qy, qz, p.x, p.y, p.z);
        unsigned long long kk =
            ((unsigned long long)__float_as_uint(u) << 32) | (unsigned)i;
        if (kk < kb[NK - 1]) {
#pragma unroll
          for (int j = 0; j < NK; j++) {
            const bool c2 = kk < kb[j];
            const unsigned long long lo = c2 ? kk : kb[j];
            const unsigned long long hi = c2 ? kb[j] : kk;
            kb[j] = lo;
            kk = hi;
          }
        }
      }
    } else {
      // safety fallback: exact full scan (correct regardless of filter)
      for (int i = 0; i < NN; i++) {
        const float4 p = pts4[slot4(i)];
        const float u = d2rn(qx, qy, qz, p.x, p.y, p.z);
        unsigned long long kk =
            ((unsigned long long)__float_as_uint(u) << 32) | (unsigned)i;
        if (kk < kb[NK - 1]) {
#pragma unroll
          for (int j = 0; j < NK; j++) {
            const bool c2 = kk < kb[j];
            const unsigned long long lo = c2 ? kk : kb[j];
            const unsigned long long hi = c2 ? kb[j] : kk;
            kb[j] = lo;
            kk = hi;
          }
        }
      }
    }
#pragma unroll
    for (int j = 0; j < NK; j++)
      cand[ql * CAP + j] = (unsigned short)(unsigned)kb[j];
  }
  __syncthreads();  // publish sorted indices

  // ---- output: each lane writes 2 neighbors (6 floats, scalar stores) ----
  float* o = out_knn + ((size_t)(b * NM + q)) * (NK * 3);
#pragma unroll
  for (int jj = 0; jj < 2; jj++) {
    const int j = part * 2 + jj;
    const int i = cand[ql * CAP + j];
    const float4 p = pts4[slot4(i)];
    o[3 * j + 0] = p.x;
    o[3 * j + 1] = p.y;
    o[3 * j + 2] = p.z;
  }
}

// ---------------------------------------------------------------------------
extern "C" void kernel_launch(void* const* d_in, const int* in_sizes, int n_in,
                              void* d_out, int out_size, void* d_ws,
                              size_t ws_size, hipStream_t stream) {
  const float* xyz      = (const float*)d_in[0];  // [8,2048,3]
  const float* xyz_fp   = (const float*)d_in[1];  // [8,8192,3]
  const float* features = (const float*)d_in[2];  // [8,64,2048]
  const float* W1 = (const float*)d_in[4];        // [64,64]
  const float* b1 = (const float*)d_in[5];        // [64]

  float* out_feats = (float*)d_out;                       // 8*2048*64
  float* out_knn   = out_feats + (size_t)NB * NN * NC;    // 8*8192*16*3
  float* out_x     = out_knn + (size_t)NB * NM * NK * 3;  // 8*2048*64

  feats_linear_kernel<<<dim3(NN / 64, NB), 256, 0, stream>>>(
      features, W1, b1, out_feats, out_x);
  knn_kernel<<<dim3(NM / QPB, NB), THREADS, 0, stream>>>(xyz, xyz_fp, out_knn);
}

// Round 8
// 203.394 us; speedup vs baseline: 1.0100x; 1.0100x over previous
//
#include <hip/hip_runtime.h>

#define NB 8
#define NN 2048
#define NM 8192
#define NC 64
#define ND 64
#define NK 16

#define PARTS 8     // lanes per query
#define PPT 256     // points per lane
#define QPB 64      // queries per block
#define THREADS 512
#define NG 8        // groups of 32 points per lane
#define G4 33       // float4 units per group (32 + 1 pad -> +1 quad shift)
#define CH4 265     // float4 units per part (8*33 + 1 -> +1 quad shift)
#define CAP 40      // candidate slots per query
#define TMARGIN 2.0e-3f  // >= 60x worst-case numeric error of the t-filter

// ---------------------------------------------------------------------------
// Kernel 1: feats = transpose(features), x = feats @ W1^T + b1  (unchanged)
// ---------------------------------------------------------------------------
__global__ __launch_bounds__(256) void feats_linear_kernel(
    const float* __restrict__ features, const float* __restrict__ W1,
    const float* __restrict__ b1, float* __restrict__ out_feats,
    float* __restrict__ out_x) {
  __shared__ float tile[NC][68];
  __shared__ float Wt[NC][68];

  const int b = blockIdx.y;
  const int n0 = blockIdx.x * 64;
  const int t = threadIdx.x;
  const int lane = t & 63;
  const int grp = t >> 6;

  for (int c = grp; c < NC; c += 4)
    tile[c][lane] = features[((size_t)(b * NC + c) * NN) + n0 + lane];
  for (int i = t; i < NC * ND; i += 256) {
    const int d = i >> 6, c = i & 63;
    Wt[c][d] = W1[i];
  }
  __syncthreads();

  for (int j = grp; j < 64; j += 4)
    out_feats[((size_t)(b * NN + n0 + j) * NC) + lane] = tile[lane][j];

  const int d = lane;
  float acc[16];
  const float bd = b1[d];
#pragma unroll
  for (int jj = 0; jj < 16; jj++) acc[jj] = bd;

  const float4* tv = (const float4*)&tile[0][0];
  for (int c = 0; c < NC; c++) {
    const float w = Wt[c][d];
#pragma unroll
    for (int q = 0; q < 4; q++) {
      const float4 v = tv[c * 17 + grp * 4 + q];
      acc[q * 4 + 0] = fmaf(v.x, w, acc[q * 4 + 0]);
      acc[q * 4 + 1] = fmaf(v.y, w, acc[q * 4 + 1]);
      acc[q * 4 + 2] = fmaf(v.z, w, acc[q * 4 + 2]);
      acc[q * 4 + 3] = fmaf(v.w, w, acc[q * 4 + 3]);
    }
  }
#pragma unroll
  for (int jj = 0; jj < 16; jj++) {
    const int j = grp * 16 + jj;
    out_x[((size_t)(b * NN + n0 + j) * ND) + d] = acc[jj];
  }
}

// ---------------------------------------------------------------------------
// Kernel 2: exact stable kNN. AoS (x,y,z,|p|^2) LDS, t-space filter,
// barrier-gated serial exact phase 3 (R6-proven structure).
// Only change vs R6: __launch_bounds__ (512,8) -> (512,4) to stop spills.
// ---------------------------------------------------------------------------
__device__ __forceinline__ float d2rn(float qx, float qy, float qz, float x,
                                      float y, float z) {
  const float dx = __fsub_rn(qx, x);
  const float dy = __fsub_rn(qy, y);
  const float dz = __fsub_rn(qz, z);
  return __fadd_rn(__fadd_rn(__fmul_rn(dx, dx), __fmul_rn(dy, dy)),
                   __fmul_rn(dz, dz));
}

__device__ __forceinline__ int slot4(int i) {
  return (i >> 8) * CH4 + ((i & 255) >> 5) * G4 + (i & 31);
}

#define CE(a, i, j)                     \
  {                                     \
    const float lo = fminf(a[i], a[j]); \
    const float hi = fmaxf(a[i], a[j]); \
    a[i] = lo;                          \
    a[j] = hi;                          \
  }

#define SORT8(d)                                  \
  CE(d, 0, 1) CE(d, 2, 3) CE(d, 4, 5) CE(d, 6, 7) \
  CE(d, 0, 2) CE(d, 1, 3) CE(d, 4, 6) CE(d, 5, 7) \
  CE(d, 1, 2) CE(d, 5, 6)                         \
  CE(d, 0, 4) CE(d, 1, 5) CE(d, 2, 6) CE(d, 3, 7) \
  CE(d, 2, 4) CE(d, 3, 5)                         \
  CE(d, 1, 2) CE(d, 3, 4) CE(d, 5, 6)

#define BITONIC16(L)                                                      \
  CE(L, 0, 8) CE(L, 1, 9) CE(L, 2, 10) CE(L, 3, 11) CE(L, 4, 12)          \
  CE(L, 5, 13) CE(L, 6, 14) CE(L, 7, 15)                                  \
  CE(L, 0, 4) CE(L, 1, 5) CE(L, 2, 6) CE(L, 3, 7) CE(L, 8, 12)            \
  CE(L, 9, 13) CE(L, 10, 14) CE(L, 11, 15)                                \
  CE(L, 0, 2) CE(L, 1, 3) CE(L, 4, 6) CE(L, 5, 7) CE(L, 8, 10)            \
  CE(L, 9, 11) CE(L, 12, 14) CE(L, 13, 15)                                \
  CE(L, 0, 1) CE(L, 2, 3) CE(L, 4, 5) CE(L, 6, 7) CE(L, 8, 9)             \
  CE(L, 10, 11) CE(L, 12, 13) CE(L, 14, 15)

__global__ __launch_bounds__(THREADS, 4) void knn_kernel(
    const float* __restrict__ xyz, const float* __restrict__ xyz_fp,
    float* __restrict__ out_knn) {
  __shared__ float4 pts4[PARTS * CH4];          // 33920 B
  __shared__ unsigned short cand[QPB * CAP];    // 5120 B
  __shared__ int ccnt[QPB];                     // 256 B

  const int b = blockIdx.y;
  const int t = threadIdx.x;
  const int ql = t >> 3;   // 0..63
  const int part = t & 7;  // 0..7

  if (t < QPB) ccnt[t] = 0;

  // ---- stage points as (x, y, z, |p|^2) ----
  const float* P = xyz + (size_t)b * NN * 3;
  for (int i = t; i < NN; i += THREADS) {
    const float x = P[3 * i + 0], y = P[3 * i + 1], z = P[3 * i + 2];
    pts4[slot4(i)] = make_float4(x, y, z, fmaf(x, x, fmaf(y, y, z * z)));
  }
  __syncthreads();

  const int q = blockIdx.x * QPB + ql;
  const float* Q = xyz_fp + ((size_t)b * NM + q) * 3;
  const float qx = Q[0], qy = Q[1], qz = Q[2];
  const float n2x = -2.0f * qx, n2y = -2.0f * qy, n2z = -2.0f * qz;

  const int pbase = part * CH4;

  // ---- pass 1: per-group min of t = d2 - |q|^2 (monotone in d2) ----
  float gmin[NG];
#pragma unroll
  for (int g = 0; g < NG; g++) {
    const int gb = pbase + g * G4;
    float gm = 3.0e38f;
#pragma unroll
    for (int s = 0; s < 8; s++) {
      const float4 p0 = pts4[gb + s * 4 + 0];
      const float4 p1 = pts4[gb + s * 4 + 1];
      const float4 p2 = pts4[gb + s * 4 + 2];
      const float4 p3 = pts4[gb + s * 4 + 3];
      const float t0 = fmaf(p0.x, n2x, fmaf(p0.y, n2y, fmaf(p0.z, n2z, p0.w)));
      const float t1 = fmaf(p1.x, n2x, fmaf(p1.y, n2y, fmaf(p1.z, n2z, p1.w)));
      const float t2 = fmaf(p2.x, n2x, fmaf(p2.y, n2y, fmaf(p2.z, n2z, p2.w)));
      const float t3 = fmaf(p3.x, n2x, fmaf(p3.y, n2y, fmaf(p3.z, n2z, p3.w)));
      gm = fminf(gm, fminf(fminf(t0, t1), fminf(t2, t3)));
    }
    gmin[g] = gm;
  }

  // ---- T = 16th-smallest of the 64 group-mins (16 distinct points ->
  //      certified upper bound); margin covers t-vs-d2 rounding ----
  float s[16];
  {
    float g8[NG];
#pragma unroll
    for (int g = 0; g < NG; g++) g8[g] = gmin[g];
    SORT8(g8)
#pragma unroll
    for (int j = 0; j < 8; j++) s[j] = g8[j];
#pragma unroll
    for (int j = 8; j < 16; j++) s[j] = 3.0e38f;
  }
#pragma unroll
  for (int mask = 1; mask <= 4; mask <<= 1) {
    float B[16];
#pragma unroll
    for (int j = 0; j < 16; j++) B[j] = __shfl_xor(s[j], mask, 64);
    float L[16];
#pragma unroll
    for (int j = 0; j < 16; j++) L[j] = fminf(s[j], B[15 - j]);
    BITONIC16(L)
#pragma unroll
    for (int j = 0; j < 16; j++) s[j] = L[j];
  }
  const float Tf = s[15] + TMARGIN;

  // ---- pass 2: scan groups with gmin <= Tf, append candidates ----
  int gm_mask = 0;
#pragma unroll
  for (int g = 0; g < NG; g++) gm_mask |= (gmin[g] <= Tf) ? (1 << g) : 0;

  while (gm_mask) {
    const int g = __ffs(gm_mask) - 1;
    gm_mask &= gm_mask - 1;
    const int gb = pbase + g * G4;
    const int ibase = part * PPT + g * 32;
#pragma unroll
    for (int s2 = 0; s2 < 8; s2++) {
      const float4 p0 = pts4[gb + s2 * 4 + 0];
      const float4 p1 = pts4[gb + s2 * 4 + 1];
      const float4 p2 = pts4[gb + s2 * 4 + 2];
      const float4 p3 = pts4[gb + s2 * 4 + 3];
      const float t0 = fmaf(p0.x, n2x, fmaf(p0.y, n2y, fmaf(p0.z, n2z, p0.w)));
      const float t1 = fmaf(p1.x, n2x, fmaf(p1.y, n2y, fmaf(p1.z, n2z, p1.w)));
      const float t2 = fmaf(p2.x, n2x, fmaf(p2.y, n2y, fmaf(p2.z, n2z, p2.w)));
      const float t3 = fmaf(p3.x, n2x, fmaf(p3.y, n2y, fmaf(p3.z, n2z, p3.w)));
      if (fminf(fminf(t0, t1), fminf(t2, t3)) <= Tf) {
        if (t0 <= Tf) {
          const int pos = atomicAdd(&ccnt[ql], 1);
          if (pos < CAP) cand[ql * CAP + pos] = (unsigned short)(ibase + s2 * 4 + 0);
        }
        if (t1 <= Tf) {
          const int pos = atomicAdd(&ccnt[ql], 1);
          if (pos < CAP) cand[ql * CAP + pos] = (unsigned short)(ibase + s2 * 4 + 1);
        }
        if (t2 <= Tf) {
          const int pos = atomicAdd(&ccnt[ql], 1);
          if (pos < CAP) cand[ql * CAP + pos] = (unsigned short)(ibase + s2 * 4 + 2);
        }
        if (t3 <= Tf) {
          const int pos = atomicAdd(&ccnt[ql], 1);
          if (pos < CAP) cand[ql * CAP + pos] = (unsigned short)(ibase + s2 * 4 + 3);
        }
      }
    }
  }
  __syncthreads();  // publish cand/ccnt to all lanes

  // ---- phase 3: exact stable top-16 by (d2, idx) u64 chain (R6-proven) ----
  if (part == 0) {
    const int cnt = ccnt[ql];
    unsigned long long kb[NK];
#pragma unroll
    for (int j = 0; j < NK; j++) kb[j] = ~0ULL;

    if (cnt >= NK && cnt <= CAP) {
      for (int c = 0; c < cnt; c++) {
        const int i = cand[ql * CAP + c];
        const float4 p = pts4[slot4(i)];
        const float u = d2rn(qx, qy, qz, p.x, p.y, p.z);
        unsigned long long kk =
            ((unsigned long long)__float_as_uint(u) << 32) | (unsigned)i;
        if (kk < kb[NK - 1]) {
#pragma unroll
          for (int j = 0; j < NK; j++) {
            const bool c2 = kk < kb[j];
            const unsigned long long lo = c2 ? kk : kb[j];
            const unsigned long long hi = c2 ? kb[j] : kk;
            kb[j] = lo;
            kk = hi;
          }
        }
      }
    } else {
      // safety fallback: exact full scan (correct regardless of filter)
      for (int i = 0; i < NN; i++) {
        const float4 p = pts4[slot4(i)];
        const float u = d2rn(qx, qy, qz, p.x, p.y, p.z);
        unsigned long long kk =
            ((unsigned long long)__float_as_uint(u) << 32) | (unsigned)i;
        if (kk < kb[NK - 1]) {
#pragma unroll
          for (int j = 0; j < NK; j++) {
            const bool c2 = kk < kb[j];
            const unsigned long long lo = c2 ? kk : kb[j];
            const unsigned long long hi = c2 ? kb[j] : kk;
            kb[j] = lo;
            kk = hi;
          }
        }
      }
    }
#pragma unroll
    for (int j = 0; j < NK; j++)
      cand[ql * CAP + j] = (unsigned short)(unsigned)kb[j];
  }
  __syncthreads();  // publish sorted indices

  // ---- output: each lane writes 2 neighbors (6 floats, scalar stores) ----
  float* o = out_knn + ((size_t)(b * NM + q)) * (NK * 3);
#pragma unroll
  for (int jj = 0; jj < 2; jj++) {
    const int j = part * 2 + jj;
    const int i = cand[ql * CAP + j];
    const float4 p = pts4[slot4(i)];
    o[3 * j + 0] = p.x;
    o[3 * j + 1] = p.y;
    o[3 * j + 2] = p.z;
  }
}

// ---------------------------------------------------------------------------
extern "C" void kernel_launch(void* const* d_in, const int* in_sizes, int n_in,
                              void* d_out, int out_size, void* d_ws,
                              size_t ws_size, hipStream_t stream) {
  const float* xyz      = (const float*)d_in[0];  // [8,2048,3]
  const float* xyz_fp   = (const float*)d_in[1];  // [8,8192,3]
  const float* features = (const float*)d_in[2];  // [8,64,2048]
  const float* W1 = (const float*)d_in[4];        // [64,64]
  const float* b1 = (const float*)d_in[5];        // [64]

  float* out_feats = (float*)d_out;                       // 8*2048*64
  float* out_knn   = out_feats + (size_t)NB * NN * NC;    // 8*8192*16*3
  float* out_x     = out_knn + (size_t)NB * NM * NK * 3;  // 8*2048*64

  feats_linear_kernel<<<dim3(NN / 64, NB), 256, 0, stream>>>(
      features, W1, b1, out_feats, out_x);
  knn_kernel<<<dim3(NM / QPB, NB), THREADS, 0, stream>>>(xyz, xyz_fp, out_knn);
}